// Round 6
// baseline (171.714 us; speedup 1.0000x reference)
//
#include <hip/hip_runtime.h>

#define PI_F 3.14159265358979f
#define NPAD 576
#define KSPLIT 8

__device__ __forceinline__ float2 cadd(float2 a, float2 b){ return make_float2(a.x+b.x, a.y+b.y); }
__device__ __forceinline__ float2 csub(float2 a, float2 b){ return make_float2(a.x-b.x, a.y-b.y); }
__device__ __forceinline__ float2 cmul(float2 a, float2 b){ return make_float2(a.x*b.x - a.y*b.y, a.x*b.y + a.y*b.x); }
__device__ __forceinline__ float2 shfl2(float2 v, int srcLane) {
    return make_float2(__shfl(v.x, srcLane), __shfl(v.y, srcLane));
}

// XOR swizzle on complex index for FFT ping-pong buffers
#define PH(i) ((i) ^ ((((unsigned)(i))>>5)&7))

// wave-local "barrier": buffers are wave-private, DS ops retire in-order per wave.
__device__ __forceinline__ void lgkm_sync() {
    asm volatile("s_waitcnt lgkmcnt(0)" ::: "memory");
    __builtin_amdgcn_sched_barrier(0);
}

// ---------------- kernel A: softmax -> W (normalized weights, f32) ----------------
__global__ __launch_bounds__(256) void ksoftw(const float* __restrict__ sel,
                                              float* __restrict__ Wout)
{
    const int row = blockIdx.x;
    const int tid = threadIdx.x;
    const float4* p4 = (const float4*)(sel + (size_t)row * 4096);
    float4 v[4];
    float mx = -3.0e38f;
#pragma unroll
    for (int i = 0; i < 4; ++i) {
        v[i] = p4[tid + (i<<8)];
        mx = fmaxf(mx, fmaxf(fmaxf(v[i].x, v[i].y), fmaxf(v[i].z, v[i].w)));
    }
#pragma unroll
    for (int o = 32; o >= 1; o >>= 1) mx = fmaxf(mx, __shfl_xor(mx, o));
    __shared__ float red[8];
    const int wv = tid >> 6;
    if ((tid & 63) == 0) red[wv] = mx;
    __syncthreads();
    mx = fmaxf(fmaxf(red[0], red[1]), fmaxf(red[2], red[3]));
    float s = 0.0f;
#pragma unroll
    for (int i = 0; i < 4; ++i) {
        s += __expf(v[i].x - mx) + __expf(v[i].y - mx) + __expf(v[i].z - mx) + __expf(v[i].w - mx);
    }
#pragma unroll
    for (int o = 32; o >= 1; o >>= 1) s += __shfl_xor(s, o);
    if ((tid & 63) == 0) red[4 + wv] = s;
    __syncthreads();
    const float inv = 1.0f / (red[4] + red[5] + red[6] + red[7]);
    float4* w4 = (float4*)(Wout + (size_t)row * 4096);
#pragma unroll
    for (int i = 0; i < 4; ++i) {
        float4 e;
        e.x = __expf(v[i].x - mx) * inv;
        e.y = __expf(v[i].y - mx) * inv;
        e.z = __expf(v[i].z - mx) * inv;
        e.w = __expf(v[i].w - mx) * inv;
        w4[tid + (i<<8)] = e;
    }
}

// ---------------- kernel B: split-K GEMM  Cpart[ks] = W[:, ks] @ items[ks, :] ----------------
__global__ __launch_bounds__(256, 2) void kgemm2(const float* __restrict__ W,
                                                 const float* __restrict__ items,
                                                 float* __restrict__ Cpart)
{
    __shared__ float As[16][68];   // [k][m]
    __shared__ float Bs[16][72];   // [k][n]
    const int tid = threadIdx.x;
    const int r0 = blockIdx.x * 64;
    const int c0 = blockIdx.y * 64;
    const int k0 = blockIdx.z * (4096 / KSPLIT);

    const int ty = tid >> 4;
    const int tx = tid & 15;
    const int am = tid >> 2;
    const int ak = (tid & 3) << 2;
    const int brow = tid >> 4;
    const int bc4 = (tid & 15) << 2;
    const int bcol = c0 + bc4;

    const float* wp = W + (size_t)(r0 + am) * 4096 + k0 + ak;

    float acc[4][4] = {{0.f}};

    for (int kt = 0; kt < (4096 / KSPLIT) / 16; ++kt) {
        const int kb = kt << 4;
        const float4 a = *(const float4*)(wp + kb);
        const float* ip = items + (size_t)(k0 + kb + brow) * 514 + bcol;
        float2 b01 = (bcol     < 514) ? *(const float2*)(ip)     : make_float2(0.f, 0.f);
        float2 b23 = (bcol + 2 < 514) ? *(const float2*)(ip + 2) : make_float2(0.f, 0.f);
        __syncthreads();
        As[ak + 0][am] = a.x;
        As[ak + 1][am] = a.y;
        As[ak + 2][am] = a.z;
        As[ak + 3][am] = a.w;
        *(float4*)&Bs[brow][bc4] = make_float4(b01.x, b01.y, b23.x, b23.y);
        __syncthreads();
#pragma unroll
        for (int kk = 0; kk < 16; ++kk) {
            const float4 av = *(const float4*)&As[kk][ty << 2];
            const float4 bv = *(const float4*)&Bs[kk][tx << 2];
            acc[0][0] = fmaf(av.x, bv.x, acc[0][0]);
            acc[0][1] = fmaf(av.x, bv.y, acc[0][1]);
            acc[0][2] = fmaf(av.x, bv.z, acc[0][2]);
            acc[0][3] = fmaf(av.x, bv.w, acc[0][3]);
            acc[1][0] = fmaf(av.y, bv.x, acc[1][0]);
            acc[1][1] = fmaf(av.y, bv.y, acc[1][1]);
            acc[1][2] = fmaf(av.y, bv.z, acc[1][2]);
            acc[1][3] = fmaf(av.y, bv.w, acc[1][3]);
            acc[2][0] = fmaf(av.z, bv.x, acc[2][0]);
            acc[2][1] = fmaf(av.z, bv.y, acc[2][1]);
            acc[2][2] = fmaf(av.z, bv.z, acc[2][2]);
            acc[2][3] = fmaf(av.z, bv.w, acc[2][3]);
            acc[3][0] = fmaf(av.w, bv.x, acc[3][0]);
            acc[3][1] = fmaf(av.w, bv.y, acc[3][1]);
            acc[3][2] = fmaf(av.w, bv.z, acc[3][2]);
            acc[3][3] = fmaf(av.w, bv.w, acc[3][3]);
        }
    }

    float* cp = Cpart + (size_t)blockIdx.z * (1024 * NPAD)
                      + (size_t)(r0 + (ty << 2)) * NPAD + c0 + (tx << 2);
#pragma unroll
    for (int i = 0; i < 4; ++i) {
        *(float4*)(cp + (size_t)i * NPAD) = make_float4(acc[i][0], acc[i][1], acc[i][2], acc[i][3]);
    }
}

// ---------------- kernel B2: reduce split-K + transform -> P planes ----------------
__global__ __launch_bounds__(256) void ktrans(const float* __restrict__ Cpart,
                                              float* __restrict__ P)
{
    const int m = blockIdx.x;
    float* Lp = P;
    float* Mp = P + 1024*257;
    float* Cp = P + 2*1024*257;
    float* Sp = P + 3*1024*257;
    for (int c = threadIdx.x; c < 514; c += 256) {
        const float* cp = Cpart + (size_t)m * NPAD + c;
        float x = 0.f;
#pragma unroll
        for (int ks = 0; ks < KSPLIT; ++ks) x += cp[(size_t)ks * (1024 * NPAD)];
        if (c < 257) {
            float mm = 0.9999f / (1.0f + __expf(-x));
            int idx = m*257 + c;
            Lp[idx] = __log2f(mm);
            Mp[idx] = mm;
        } else {
            int idx = m*257 + (c - 257);
            float e2 = __expf(2.0f*x);
            float th = (e2 - 1.0f) / (e2 + 1.0f);
            float ph = PI_F * th;
            float sn, cs;
            __sincosf(ph, &sn, &cs);
            Cp[idx] = cs;
            Sp[idx] = sn;
        }
    }
}

// ---------------- kernel C: spectral phases in registers (shfl), FFT st1/st2 in LDS ----------
// grid = 1024 items * 8 jgroups; 4 fully independent waves per block; no __syncthreads at all.
__global__ __launch_bounds__(256) void kres(const float* __restrict__ P, float* __restrict__ out)
{
    const int tid = threadIdx.x;
    const int lane = tid & 63;
    const int wv = tid >> 6;
    const int item = blockIdx.x >> 3;
    const int jg = blockIdx.x & 7;

    __shared__ float2 bufA_s[4][256];
    __shared__ float2 bufB_s[4][256];
    float2* bufA = bufA_s[wv];
    float2* bufB = bufB_s[wv];

    // stage twiddles e^{+2πi idx/256} — pure functions of lane, hoisted to regs
    const float A256 = 6.283185307179586f / 256.0f;
    float2 s0w1, s0w2, s0w3, s1w1, s1w2, s1w3, s2w1, s2w2, s2w3;
    {
        float s, c;
        const int p1 = (lane >> 2) << 2;      // 4*(lane>>2)
        const int p2 = (lane >> 4) << 4;      // 16*(lane>>4)
        __sincosf(A256 * (float)lane,     &s, &c); s0w1 = make_float2(c, s);
        __sincosf(A256 * (float)(2*lane), &s, &c); s0w2 = make_float2(c, s);
        __sincosf(A256 * (float)(3*lane), &s, &c); s0w3 = make_float2(c, s);
        __sincosf(A256 * (float)p1,       &s, &c); s1w1 = make_float2(c, s);
        __sincosf(A256 * (float)(2*p1),   &s, &c); s1w2 = make_float2(c, s);
        __sincosf(A256 * (float)(3*p1),   &s, &c); s1w3 = make_float2(c, s);
        __sincosf(A256 * (float)p2,       &s, &c); s2w1 = make_float2(c, s);
        __sincosf(A256 * (float)(2*p2),   &s, &c); s2w2 = make_float2(c, s);
        __sincosf(A256 * (float)(3*p2),   &s, &c); s2w3 = make_float2(c, s);
    }
    // half-size-packing twiddles e^{+2πi k/512}, k = lane+64r
    float2 zwr[4];
#pragma unroll
    for (int r = 0; r < 4; ++r) {
        float s, c;
        __sincosf((6.283185307179586f/512.0f) * (float)(lane + (r<<6)), &s, &c);
        zwr[r] = make_float2(c, s);
    }

    const float* Lp = P;
    const float* Mp = P + 1024*257;
    const float* Cp = P + 2*1024*257;
    const float* Sp = P + 3*1024*257;
    const int pb = item * 257;

    float l[4], mg[4], cf[4], sf[4];
#pragma unroll
    for (int r = 0; r < 4; ++r) {
        int c = lane + (r<<6);
        l[r]  = Lp[pb + c];
        mg[r] = Mp[pb + c];
        cf[r] = Cp[pb + c];
        sf[r] = Sp[pb + c];
    }
    const float l6 = Lp[pb + 256];
    const float m6 = Mp[pb + 256];
    const float c6 = Cp[pb + 256];

    float2* outbase = (float2*)out + (size_t)item * 16384;
    const int dn = (lane + 63) & 63;
    const int up = (lane + 1) & 63;
    const int mlane = (64 - lane) & 63;

    for (int t = 0; t < 4; ++t) {
        const int j = jg*16 + wv + (t<<2);
        const float gf = (j > 0) ? 1.0f : 0.0f;
        const float fj = (float)j;
        const float g = (lane & 1) ? -gf : gf;   // (-1)^c, c = lane+64r (64r even)

        // ---- S = F_j + (-1)^c F_{j-1},  V = F_j - (-1)^c F_{j-1}  (registers)
        float2 S[4], V[4];
#pragma unroll
        for (int r = 0; r < 4; ++r) {
            float p = exp2f(fj * l[r]);
            float pc = p * cf[r], ps = p * sf[r];
            float mpc = mg[r] * pc, mps = mg[r] * ps;
            float2 Sv = make_float2(fmaf(g, pc, mpc), fmaf(g, ps, mps));
            float2 Vv = make_float2(fmaf(-g, pc, mpc), fmaf(-g, ps, mps));
            if (r == 0 && lane == 0) { Sv.y = 0.0f; Vv.y = 0.0f; }  // DC imag dropped
            S[r] = Sv; V[r] = Vv;
        }
        const float p6 = exp2f(fj * l6);
        const float S6 = p6 * (m6 + gf) * c6;    // bin 256 (real)
        const float V6 = p6 * (m6 - gf) * c6;

        // ---- Hann 3-tap: H[c] = 0.5 S[c] - 0.25 (V[c-1] + V[c+1]) — via shuffles
        float2 b63[3], b0h[4], v1;
        b63[0] = shfl2(V[0], 63); b63[1] = shfl2(V[1], 63); b63[2] = shfl2(V[2], 63);
        b0h[1] = shfl2(V[1], 0);  b0h[2] = shfl2(V[2], 0);  b0h[3] = shfl2(V[3], 0);
        v1 = shfl2(V[0], 1);
        const float v255x = __shfl(V[3].x, 63);
        float2 H[4];
#pragma unroll
        for (int r = 0; r < 4; ++r) {
            float2 vm = shfl2(V[r], dn);
            float2 vp = shfl2(V[r], up);
            if (lane == 0)  vm = (r == 0) ? make_float2(v1.x, -v1.y) : b63[r-1];
            if (lane == 63) vp = (r == 3) ? make_float2(V6, 0.f)     : b0h[r+1];
            H[r] = make_float2(0.5f*S[r].x - 0.25f*(vm.x + vp.x),
                               0.5f*S[r].y - 0.25f*(vm.y + vp.y));
        }
        const float H6 = 0.5f*S6 - 0.5f*v255x;   // bin 256 (real)

        // ---- half-size packing: Z[k] = (1/512)[H[k](1+iw) + conj(H[256-k])(1-iw)]
        float2 Z[4];
#pragma unroll
        for (int r = 0; r < 4; ++r) {
            float2 Hm = shfl2(H[3-r], mlane);    // lane 64-l, slot 3-r  (l>=1)
            if (lane == 0) Hm = (r == 0) ? make_float2(H6, 0.f)
                                         : ((r == 1) ? H[3] : ((r == 2) ? H[2] : H[1]));
            float2 w = zwr[r];
            float Ar = H[r].x + Hm.x, Ai = H[r].y - Hm.y;
            float Br = H[r].x - Hm.x, Bi = H[r].y + Hm.y;
            float iwr = -w.y*Br - w.x*Bi;
            float iwi =  w.x*Br - w.y*Bi;
            Z[r] = make_float2((Ar + iwr)*(1.0f/512.0f), (Ai + iwi)*(1.0f/512.0f));
        }

        // ---- FFT stage 0 (s=1): lane-local slots are exactly {k, k+64, k+128, k+192}
        {
            float2 apc = cadd(Z[0], Z[2]), amc = csub(Z[0], Z[2]);
            float2 bpd = cadd(Z[1], Z[3]);
            float2 jb = make_float2(Z[3].y - Z[1].y, Z[1].x - Z[3].x);
            const int base = lane << 2;
            bufA[PH(base + 0)] = cadd(apc, bpd);
            bufA[PH(base + 1)] = cmul(s0w1, cadd(amc, jb));
            bufA[PH(base + 2)] = cmul(s0w2, csub(apc, bpd));
            bufA[PH(base + 3)] = cmul(s0w3, csub(amc, jb));
        }
        lgkm_sync();

        // ---- FFT stage 1 (s=4)
        {
            float2 A = bufA[PH(lane)];
            float2 B = bufA[PH(lane + 64)];
            float2 C = bufA[PH(lane + 128)];
            float2 D = bufA[PH(lane + 192)];
            float2 apc = cadd(A, C), amc = csub(A, C);
            float2 bpd = cadd(B, D);
            float2 jb = make_float2(D.y - B.y, B.x - D.x);
            const int ob = (lane & 3) + ((lane >> 2) << 4);
            bufB[PH(ob)]      = cadd(apc, bpd);
            bufB[PH(ob + 4)]  = cmul(s1w1, cadd(amc, jb));
            bufB[PH(ob + 8)]  = cmul(s1w2, csub(apc, bpd));
            bufB[PH(ob + 12)] = cmul(s1w3, csub(amc, jb));
        }
        lgkm_sync();

        // ---- FFT stage 2 (s=16)
        {
            float2 A = bufB[PH(lane)];
            float2 B = bufB[PH(lane + 64)];
            float2 C = bufB[PH(lane + 128)];
            float2 D = bufB[PH(lane + 192)];
            float2 apc = cadd(A, C), amc = csub(A, C);
            float2 bpd = cadd(B, D);
            float2 jb = make_float2(D.y - B.y, B.x - D.x);
            const int ob = (lane & 15) + ((lane >> 4) << 6);
            bufA[PH(ob)]      = cadd(apc, bpd);
            bufA[PH(ob + 16)] = cmul(s2w1, cadd(amc, jb));
            bufA[PH(ob + 32)] = cmul(s2w2, csub(apc, bpd));
            bufA[PH(ob + 48)] = cmul(s2w3, csub(amc, jb));
        }
        lgkm_sync();

        // ---- stage 3 fused (twiddles=1, lower half only) + store
        {
            float2 A = bufA[PH(lane)];
            float2 B = bufA[PH(lane + 64)];
            float2 C = bufA[PH(lane + 128)];
            float2 D = bufA[PH(lane + 192)];
            float2 apc = cadd(A, C), amc = csub(A, C);
            float2 bpd = cadd(B, D);
            float2 jb = make_float2(D.y - B.y, B.x - D.x);
            float2 y0 = cadd(apc, bpd);
            float2 y1 = cadd(amc, jb);
            float2* o2 = outbase + (j << 7);
            o2[lane] = y0;
            o2[lane + 64] = y1;
        }
        lgkm_sync();   // WAR guard: stage-3 reads drained before next-t stage-0 writes
    }
}

extern "C" void kernel_launch(void* const* d_in, const int* in_sizes, int n_in,
                              void* d_out, int out_size, void* d_ws, size_t ws_size,
                              hipStream_t stream)
{
    const float* sel   = (const float*)d_in[0];   // (8,32,4,4096) f32 -> [1024][4096]
    const float* items = (const float*)d_in[1];   // (4096,514) f32
    float* out = (float*)d_out;                   // [1024][32768] f32
    float* ws  = (float*)d_ws;

    float* W     = out;                  // 1024*4096 floats (scratch in d_out)
    float* Cpart = out + 4194304;        // KSPLIT*1024*NPAD floats
    float* P     = ws;                   // 4*1024*257 floats

    ksoftw<<<1024, 256, 0, stream>>>(sel, W);
    dim3 g2(16, 9, KSPLIT);
    kgemm2<<<g2, 256, 0, stream>>>(W, items, Cpart);
    ktrans<<<1024, 256, 0, stream>>>(Cpart, P);
    kres<<<8192, 256, 0, stream>>>(P, out);
}